// Round 8
// baseline (484.098 us; speedup 1.0000x reference)
//
#include <hip/hip_runtime.h>
#include <cstdint>

typedef unsigned long long u64;
typedef unsigned short u16;

#define HWSZ 3136      // 56*56
#define WD 56
#define NPIX 50176     // 16*3136
#define HS 58          // halo row stride
#define IMG 3364       // 58*58 positions per image

__device__ __forceinline__ float clampf(float v){ return fminf(1.0f, fmaxf(-1.0f, v)); }
__device__ __forceinline__ u16 f2bf(float f){
    unsigned u = __float_as_uint(f);
    return (u16)((u + 0x7fffu + ((u >> 16) & 1u)) >> 16);
}
__device__ __forceinline__ float bf2f(u16 h){ return __uint_as_float(((unsigned)h) << 16); }
// xor + chained popcount: should emit 2 v_xor + 2 v_bcnt (add folded into bcnt src1)
__device__ __forceinline__ int xp(u64 a, u64 b, int s){
    u64 x = a ^ b;
    s += __popc((unsigned)x);
    s += __popc((unsigned)(x >> 32));
    return s;
}

// one 3x3 binary-conv pass over a halo'd bit tensor; no masks, no clamps.
// wsrc may be LDS or global (wave-uniform colbase -> broadcast / scalar loads).
__device__ __forceinline__ void conv_pass(
    const u64* __restrict__ bits, const u64* __restrict__ wsrc, int colbase,
    int base, int (&accA)[8][2], int (&accB)[8][2])
{
#pragma unroll 1
    for (int dy = -1; dy <= 1; dy++) {
        const ulonglong2* rp = (const ulonglong2*)(bits + (size_t)(base + dy * HS) * 4);
        ulonglong2 plo[4], phi[4];
#pragma unroll
        for (int k = 0; k < 4; k++) { plo[k] = rp[2 * k]; phi[k] = rp[2 * k + 1]; }
        int tb = (dy + 1) * 3;
#pragma unroll
        for (int dx = 0; dx < 3; dx++) {
#pragma unroll
            for (int co = 0; co < 8; co++) {
                const u64* wp = wsrc + ((size_t)(colbase + co) * 9 + tb + dx) * 4;
                u64 wa0 = wp[0], wa1 = wp[1], wb0 = wp[2], wb1 = wp[3];
#pragma unroll
                for (int p = 0; p < 2; p++) {
                    int k = dx + p; int s = accA[co][p];
                    s = xp(plo[k].x, wa0, s); s = xp(plo[k].y, wa1, s);
                    s = xp(phi[k].x, wb0, s); s = xp(phi[k].y, wb1, s);
                    accA[co][p] = s;
                }
            }
#pragma unroll
            for (int co = 0; co < 8; co++) {
                const u64* wp = wsrc + ((size_t)(colbase + 8 + co) * 9 + tb + dx) * 4;
                u64 wa0 = wp[0], wa1 = wp[1], wb0 = wp[2], wb1 = wp[3];
#pragma unroll
                for (int p = 0; p < 2; p++) {
                    int k = dx + p; int s = accB[co][p];
                    s = xp(plo[k].x, wa0, s); s = xp(plo[k].y, wa1, s);
                    s = xp(phi[k].x, wb0, s); s = xp(phi[k].y, wb1, s);
                    accB[co][p] = s;
                }
            }
        }
    }
}

// ---------------- weight prep: pack sign bits, fold bn, border-correction sums ----
__global__ __launch_bounds__(256) void k_wprep(
    const float* __restrict__ w1, const float* __restrict__ w2,
    const float* __restrict__ g1, const float* __restrict__ be1,
    const float* __restrict__ m1, const float* __restrict__ v1,
    const float* __restrict__ g2, const float* __restrict__ be2,
    const float* __restrict__ m2, const float* __restrict__ v2,
    u64* __restrict__ w1b, u64* __restrict__ w2e, u64* __restrict__ w2o,
    float* __restrict__ A1, float* __restrict__ B1,
    float* __restrict__ A2, float* __restrict__ B2,
    int* __restrict__ C1s, int* __restrict__ C2s)
{
    int co  = blockIdx.x;
    int tid = threadIdx.x;
    int wv = tid >> 6, lane = tid & 63;
    int ci = (wv << 6) + lane;

    __shared__ int spc1[4][9], spc2[4][9];

    float s1 = 0.f, s2 = 0.f;
    const float* w1p = w1 + ((size_t)co * 256 + ci) * 9;
#pragma unroll
    for (int t = 0; t < 9; t++) {
        float v = w1p[t];
        s1 += fabsf(v);
        u64 bal = __ballot(v >= 0.f);
        if (lane == 0) { w1b[(co * 9 + t) * 4 + wv] = bal; spc1[wv][t] = __popcll(bal); }
    }
    const float* wep = w2 + ((size_t)co * 512 + 2 * ci) * 9;
    const float* wop = wep + 9;
#pragma unroll
    for (int t = 0; t < 9; t++) {
        float ve = wep[t], vo = wop[t];
        s2 += fabsf(ve) + fabsf(vo);
        u64 bale = __ballot(ve >= 0.f);
        u64 balo = __ballot(vo >= 0.f);
        if (lane == 0) {
            w2e[(co * 9 + t) * 4 + wv] = bale; w2o[(co * 9 + t) * 4 + wv] = balo;
            spc2[wv][t] = __popcll(bale) + __popcll(balo);
        }
    }
    __shared__ float red1[256], red2[256];
    red1[tid] = s1; red2[tid] = s2;
    __syncthreads();
    for (int off = 128; off > 0; off >>= 1) {
        if (tid < off) { red1[tid] += red1[tid + off]; red2[tid] += red2[tid + off]; }
        __syncthreads();
    }
    if (tid == 0) {
        float scale1 = red1[0] / 2304.f;
        float scale2 = red2[0] / 4608.f;
        float inv1 = g1[co] / sqrtf(v1[co] + 1e-5f);
        float inv2 = g2[co] / sqrtf(v2[co] + 1e-5f);
        A1[co] = scale1 * inv1;  B1[co] = be1[co] - m1[co] * inv1;
        A2[co] = scale2 * inv2;  B2[co] = be2[co] - m2[co] * inv2;
        int pc1[9], pc2[9];
#pragma unroll
        for (int t = 0; t < 9; t++) {
            pc1[t] = spc1[0][t] + spc1[1][t] + spc1[2][t] + spc1[3][t];
            pc2[t] = spc2[0][t] + spc2[1][t] + spc2[2][t] + spc2[3][t];
        }
        int* c1 = C1s + co * 8;
        c1[0] = pc1[0] + pc1[1] + pc1[2];   // ST (top row invalid)
        c1[1] = pc1[6] + pc1[7] + pc1[8];   // SB
        c1[2] = pc1[0] + pc1[3] + pc1[6];   // SL
        c1[3] = pc1[2] + pc1[5] + pc1[8];   // SR
        c1[4] = pc1[0]; c1[5] = pc1[2]; c1[6] = pc1[6]; c1[7] = pc1[8];
        int* c2 = C2s + co * 8;
        c2[0] = pc2[0] + pc2[1] + pc2[2];
        c2[1] = pc2[6] + pc2[7] + pc2[8];
        c2[2] = pc2[0] + pc2[3] + pc2[6];
        c2[3] = pc2[2] + pc2[5] + pc2[8];
        c2[4] = pc2[0]; c2[5] = pc2[2]; c2[6] = pc2[6]; c2[7] = pc2[8];
    }
}

// ---------------- zero the halo'd bit arrays ----------------
__global__ __launch_bounds__(256) void k_zero(ulonglong2* __restrict__ dst, int n)
{
    int i = blockIdx.x * 256 + threadIdx.x;
    if (i < n) { ulonglong2 z; z.x = 0; z.y = 0; dst[i] = z; }
}

// ---------------- activation packing into halo'd arrays ----------------
__global__ __launch_bounds__(256) void k_pack(
    const float* __restrict__ x, const float* __restrict__ mb,
    u64* __restrict__ bitsA, u64* __restrict__ bitsI)
{
    int tid = threadIdx.x;
    int p = blockIdx.x * 256 + tid;
    int q = blockIdx.y;
    int b = p / HWSZ, hw = p % HWSZ;
    int h = hw / WD, w = hw % WD;
    const float* xa = x + ((size_t)(b * 512 + q * 64)) * HWSZ + hw;
    const float* xi = x + ((size_t)(b * 512 + 256 + q * 64)) * HWSZ + hw;
    const float* mbq = mb + q * 64;
    u64 wa = 0, wi = 0;
#pragma unroll 8
    for (int j = 0; j < 64; j++) {
        float va = xa[(size_t)j * HWSZ];
        float vi = xi[(size_t)j * HWSZ] + mbq[j];
        wa |= (u64)(va >= 0.f) << j;
        wi |= (u64)(vi >= 0.f) << j;
    }
    size_t pos = ((size_t)b * IMG + (h + 1) * HS + (w + 1)) * 4 + q;
    bitsA[pos] = wa;
    bitsI[pos] = wi;
}

// ---------------- conv1: scalar-cache weights (no weight LDS) ----------------
__global__ __launch_bounds__(512, 6) void k_conv1(
    const float* __restrict__ x, const u64* __restrict__ bitsA,
    const u64* __restrict__ w1b, const float* __restrict__ A1,
    const float* __restrict__ B1, const int* __restrict__ C1s,
    u64* __restrict__ bitsC, u16* __restrict__ c1v)
{
    __shared__ float sA[64], sB[64];
    __shared__ int scr[512];
    __shared__ u16 spart[4][256];
    int tid = threadIdx.x, q = blockIdx.y, cobase = q * 64;
    if (tid < 64) { sA[tid] = A1[cobase + tid]; sB[tid] = B1[cobase + tid]; }
    scr[tid] = C1s[cobase * 8 + tid];
    __syncthreads();

    int wid = tid >> 6, lane = tid & 63;
    int gu = __builtin_amdgcn_readfirstlane(wid & 3);
    int ph = wid >> 2;
    int pix0 = blockIdx.x * 256 + ph * 128 + lane * 2;
    int b = pix0 / HWSZ, hw = pix0 % HWSZ, h = hw / WD, w = hw % WD; // w even
    int base = b * IMG + (h + 1) * HS + w;

    int accA[8][2] = {}, accB[8][2] = {};
    conv_pass(bitsA, w1b, cobase + (gu << 4), base, accA, accB);

    int mt = (h == 0), mbo = (h == WD - 1);
    int wl = (w == 0), wr = (w == 54);
    int nvr = 3 - mt - mbo;
    int nv0 = nvr * (3 - wl), nv1 = nvr * (3 - wr);

    unsigned sb0 = 0, sb1 = 0;
    bool wrv = (q < 2);
#pragma unroll
    for (int half = 0; half < 2; half++)
#pragma unroll
    for (int co = 0; co < 8; co++) {
        int col = (gu << 4) + half * 8 + co;
        int coG = cobase + col, bit = half * 8 + co;
        float A = sA[col], Bc = sB[col];
        const int* cs = &scr[col * 8];
        int a0 = half ? accB[co][0] : accA[co][0];
        int a1 = half ? accB[co][1] : accA[co][1];
        int ctb = (mt ? cs[0] : 0) + (mbo ? cs[1] : 0);
        int corr0 = ctb + (wl ? (cs[2] - (mt ? cs[4] : 0) - (mbo ? cs[6] : 0)) : 0);
        int corr1 = ctb + (wr ? (cs[3] - (mt ? cs[5] : 0) - (mbo ? cs[7] : 0)) : 0);
        float2 xr = *(const float2*)(x + ((size_t)(b * 512 + coG)) * HWSZ + hw);
        float v0 = (float)((nv0 << 8) + 2 * (corr0 - a0)) * A + Bc + xr.x;
        float v1 = (float)((nv1 << 8) + 2 * (corr1 - a1)) * A + Bc + xr.y;
        sb0 |= (unsigned)(v0 >= 0.f) << bit;
        sb1 |= (unsigned)(v1 >= 0.f) << bit;
        if (wrv) {
            ushort2 st; st.x = f2bf(clampf(v0)); st.y = f2bf(clampf(v1));
            *(ushort2*)(c1v + (size_t)coG * NPIX + pix0) = st;
        }
    }
    spart[gu][ph * 128 + lane * 2]     = (u16)sb0;
    spart[gu][ph * 128 + lane * 2 + 1] = (u16)sb1;
    __syncthreads();
    if ((wid & 3) == 0) {
#pragma unroll
        for (int p = 0; p < 2; p++) {
            int pi = ph * 128 + lane * 2 + p;
            u64 word = (u64)spart[0][pi] | ((u64)spart[1][pi] << 16)
                     | ((u64)spart[2][pi] << 32) | ((u64)spart[3][pi] << 48);
            bitsC[(size_t)(base + 1 + p) * 4 + q] = word;
        }
    }
}

// ---------------- conv2: LDS weights, two passes share acc ----------------
__global__ __launch_bounds__(512, 6) void k_conv2(
    const float* __restrict__ x, const float* __restrict__ mb,
    const u64* __restrict__ bitsC, const u64* __restrict__ bitsI,
    const u64* __restrict__ w2e, const u64* __restrict__ w2o,
    const float* __restrict__ A2, const float* __restrict__ B2,
    const int* __restrict__ C2s,
    const u16* __restrict__ c1v, float* __restrict__ out)
{
    __shared__ __align__(16) u64 se[2304], so[2304];
    __shared__ float sA[64], sB[64], sM[32];
    __shared__ int scr[512];
    int tid = threadIdx.x, q = blockIdx.y, cobase = q * 64;
    {
        const u64* srcE = w2e + (size_t)cobase * 36;
        const u64* srcO = w2o + (size_t)cobase * 36;
        for (int i = tid; i < 2304; i += 512) { se[i] = srcE[i]; so[i] = srcO[i]; }
        if (tid < 64) { sA[tid] = A2[cobase + tid]; sB[tid] = B2[cobase + tid]; }
        if (tid >= 64 && tid < 96) sM[tid - 64] = mb[q * 32 + tid - 64];
        scr[tid] = C2s[cobase * 8 + tid];
    }
    __syncthreads();

    int wid = tid >> 6, lane = tid & 63;
    int gu = __builtin_amdgcn_readfirstlane(wid & 3);
    int ph = wid >> 2;
    int pix0 = blockIdx.x * 256 + ph * 128 + lane * 2;
    int b = pix0 / HWSZ, hw = pix0 % HWSZ, h = hw / WD, w = hw % WD;
    int base = b * IMG + (h + 1) * HS + w;

    int accA[8][2] = {}, accB[8][2] = {};
    conv_pass(bitsC, se, gu << 4, base, accA, accB);
    conv_pass(bitsI, so, gu << 4, base, accA, accB);

    int mt = (h == 0), mbo = (h == WD - 1);
    int wl = (w == 0), wr = (w == 54);
    int nvr = 3 - mt - mbo;
    int nv0 = nvr * (3 - wl), nv1 = nvr * (3 - wr);

#pragma unroll
    for (int half = 0; half < 2; half++)
#pragma unroll
    for (int co = 0; co < 8; co++) {
        int col = (gu << 4) + half * 8 + co;
        int coG = cobase + col, cg2 = coG >> 1;
        float A = sA[col], Bc = sB[col];
        const int* cs = &scr[col * 8];
        int a0 = half ? accB[co][0] : accA[co][0];
        int a1 = half ? accB[co][1] : accA[co][1];
        int ctb = (mt ? cs[0] : 0) + (mbo ? cs[1] : 0);
        int corr0 = ctb + (wl ? (cs[2] - (mt ? cs[4] : 0) - (mbo ? cs[6] : 0)) : 0);
        int corr1 = ctb + (wr ? (cs[3] - (mt ? cs[5] : 0) - (mbo ? cs[7] : 0)) : 0);
        float r0, r1;
        if ((co & 1) == 0) {   // coG even -> conv1 output residual
            ushort2 cv = *(const ushort2*)(c1v + (size_t)cg2 * NPIX + pix0);
            r0 = bf2f(cv.x); r1 = bf2f(cv.y);
        } else {               // coG odd -> idle branch residual
            float2 xi = *(const float2*)(x + ((size_t)(b * 512 + 256 + cg2)) * HWSZ + hw);
            float mv = sM[col >> 1];
            r0 = xi.x + mv; r1 = xi.y + mv;
        }
        float2 ov;
        ov.x = clampf((float)((nv0 << 9) + 2 * (corr0 - a0)) * A + Bc + r0);
        ov.y = clampf((float)((nv1 << 9) + 2 * (corr1 - a1)) * A + Bc + r1);
        *(float2*)(out + ((size_t)(b * 256 + coG)) * HWSZ + hw) = ov;
    }
}

extern "C" void kernel_launch(void* const* d_in, const int* in_sizes, int n_in,
                              void* d_out, int out_size, void* d_ws, size_t ws_size,
                              hipStream_t stream)
{
    const float* x   = (const float*)d_in[0];
    const float* w1  = (const float*)d_in[1];
    const float* w2  = (const float*)d_in[2];
    const float* g1  = (const float*)d_in[3];
    const float* be1 = (const float*)d_in[4];
    const float* m1  = (const float*)d_in[5];
    const float* v1  = (const float*)d_in[6];
    const float* g2  = (const float*)d_in[7];
    const float* be2 = (const float*)d_in[8];
    const float* m2  = (const float*)d_in[9];
    const float* v2  = (const float*)d_in[10];
    const float* mb  = (const float*)d_in[11];

    char* ws = (char*)d_ws;
    u64* w1b = (u64*)ws; ws += 73728;
    u64* w2e = (u64*)ws; ws += 73728;
    u64* w2o = (u64*)ws; ws += 73728;
    float* A1 = (float*)ws; ws += 1024;
    float* B1 = (float*)ws; ws += 1024;
    float* A2 = (float*)ws; ws += 1024;
    float* B2 = (float*)ws; ws += 1024;
    int* C1s = (int*)ws; ws += 8192;
    int* C2s = (int*)ws; ws += 8192;
    u64* bitsA = (u64*)ws; ws += (size_t)16 * IMG * 4 * 8;   // 1722368 B
    u64* bitsI = (u64*)ws; ws += (size_t)16 * IMG * 4 * 8;
    u64* bitsC = (u64*)ws; ws += (size_t)16 * IMG * 4 * 8;
    u16* c1v = (u16*)ws; ws += (size_t)128 * NPIX * 2;

    int nzero2 = (int)(3 * (size_t)16 * IMG * 4 * 8 / 16);   // 322944 ulonglong2

    hipLaunchKernelGGL(k_wprep, dim3(256), dim3(256), 0, stream,
                       w1, w2, g1, be1, m1, v1, g2, be2, m2, v2,
                       w1b, w2e, w2o, A1, B1, A2, B2, C1s, C2s);
    hipLaunchKernelGGL(k_zero, dim3((nzero2 + 255) / 256), dim3(256), 0, stream,
                       (ulonglong2*)bitsA, nzero2);
    hipLaunchKernelGGL(k_pack, dim3(196, 4), dim3(256), 0, stream, x, mb, bitsA, bitsI);
    hipLaunchKernelGGL(k_conv1, dim3(196, 4), dim3(512), 0, stream,
                       x, bitsA, w1b, A1, B1, C1s, bitsC, c1v);
    hipLaunchKernelGGL(k_conv2, dim3(196, 4), dim3(512), 0, stream,
                       x, mb, bitsC, bitsI, w2e, w2o, A2, B2, C2s, c1v, (float*)d_out);
}

// Round 9
// 438.533 us; speedup vs baseline: 1.1039x; 1.1039x over previous
//
#include <hip/hip_runtime.h>
#include <cstdint>

typedef unsigned long long u64;
typedef unsigned short u16;

#define HWSZ 3136      // 56*56
#define WD 56
#define NPIX 50176     // 16*3136
#define HS 58          // halo row stride
#define IMG 3364       // 58*58 positions per image

__device__ __forceinline__ float clampf(float v){ return fminf(1.0f, fmaxf(-1.0f, v)); }
__device__ __forceinline__ u16 f2bf(float f){
    unsigned u = __float_as_uint(f);
    return (u16)((u + 0x7fffu + ((u >> 16) & 1u)) >> 16);
}
__device__ __forceinline__ float bf2f(u16 h){ return __uint_as_float(((unsigned)h) << 16); }
// xor + chained popcount: 2 v_xor + 2 v_bcnt (accumulate folds into bcnt src1)
__device__ __forceinline__ int xp(u64 a, u64 b, int s){
    u64 x = a ^ b;
    s += __popc((unsigned)x);
    s += __popc((unsigned)(x >> 32));
    return s;
}

// one 3x3 binary-conv pass over a halo'd bit tensor, 2 adjacent pixels/lane.
// wlds: LDS weight array; colbase wave-uniform -> broadcast ds_reads.
__device__ __forceinline__ void conv_pass2(
    const u64* __restrict__ bits, const u64* wlds, int colbase,
    int base, int (&accA)[8][2], int (&accB)[8][2])
{
#pragma unroll 1
    for (int dy = -1; dy <= 1; dy++) {
        const ulonglong2* rp = (const ulonglong2*)(bits + (size_t)(base + dy * HS) * 4);
        ulonglong2 plo[4], phi[4];
#pragma unroll
        for (int k = 0; k < 4; k++) { plo[k] = rp[2 * k]; phi[k] = rp[2 * k + 1]; }
#pragma unroll
        for (int dx = 0; dx < 3; dx++) {
            int t = (dy + 1) * 3 + dx;
#pragma unroll
            for (int co = 0; co < 8; co++) {
                const ulonglong2* wp = (const ulonglong2*)&wlds[((colbase + co) * 9 + t) * 4];
                ulonglong2 wA = wp[0], wB = wp[1];
#pragma unroll
                for (int p = 0; p < 2; p++) {
                    int k = dx + p; int s = accA[co][p];
                    s = xp(plo[k].x, wA.x, s); s = xp(plo[k].y, wA.y, s);
                    s = xp(phi[k].x, wB.x, s); s = xp(phi[k].y, wB.y, s);
                    accA[co][p] = s;
                }
            }
#pragma unroll
            for (int co = 0; co < 8; co++) {
                const ulonglong2* wp = (const ulonglong2*)&wlds[((colbase + 8 + co) * 9 + t) * 4];
                ulonglong2 wA = wp[0], wB = wp[1];
#pragma unroll
                for (int p = 0; p < 2; p++) {
                    int k = dx + p; int s = accB[co][p];
                    s = xp(plo[k].x, wA.x, s); s = xp(plo[k].y, wA.y, s);
                    s = xp(phi[k].x, wB.x, s); s = xp(phi[k].y, wB.y, s);
                    accB[co][p] = s;
                }
            }
        }
    }
}

// ---------------- weight prep: pack sign bits, fold bn, border-correction sums ----
__global__ __launch_bounds__(256) void k_wprep(
    const float* __restrict__ w1, const float* __restrict__ w2,
    const float* __restrict__ g1, const float* __restrict__ be1,
    const float* __restrict__ m1, const float* __restrict__ v1,
    const float* __restrict__ g2, const float* __restrict__ be2,
    const float* __restrict__ m2, const float* __restrict__ v2,
    u64* __restrict__ w1b, u64* __restrict__ w2e, u64* __restrict__ w2o,
    float* __restrict__ A1, float* __restrict__ B1,
    float* __restrict__ A2, float* __restrict__ B2,
    int* __restrict__ C1s, int* __restrict__ C2s)
{
    int co  = blockIdx.x;
    int tid = threadIdx.x;
    int wv = tid >> 6, lane = tid & 63;
    int ci = (wv << 6) + lane;

    __shared__ int spc1[4][9], spc2[4][9];

    float s1 = 0.f, s2 = 0.f;
    const float* w1p = w1 + ((size_t)co * 256 + ci) * 9;
#pragma unroll
    for (int t = 0; t < 9; t++) {
        float v = w1p[t];
        s1 += fabsf(v);
        u64 bal = __ballot(v >= 0.f);
        if (lane == 0) { w1b[(co * 9 + t) * 4 + wv] = bal; spc1[wv][t] = __popcll(bal); }
    }
    const float* wep = w2 + ((size_t)co * 512 + 2 * ci) * 9;
    const float* wop = wep + 9;
#pragma unroll
    for (int t = 0; t < 9; t++) {
        float ve = wep[t], vo = wop[t];
        s2 += fabsf(ve) + fabsf(vo);
        u64 bale = __ballot(ve >= 0.f);
        u64 balo = __ballot(vo >= 0.f);
        if (lane == 0) {
            w2e[(co * 9 + t) * 4 + wv] = bale; w2o[(co * 9 + t) * 4 + wv] = balo;
            spc2[wv][t] = __popcll(bale) + __popcll(balo);
        }
    }
    __shared__ float red1[256], red2[256];
    red1[tid] = s1; red2[tid] = s2;
    __syncthreads();
    for (int off = 128; off > 0; off >>= 1) {
        if (tid < off) { red1[tid] += red1[tid + off]; red2[tid] += red2[tid + off]; }
        __syncthreads();
    }
    if (tid == 0) {
        float scale1 = red1[0] / 2304.f;
        float scale2 = red2[0] / 4608.f;
        float inv1 = g1[co] / sqrtf(v1[co] + 1e-5f);
        float inv2 = g2[co] / sqrtf(v2[co] + 1e-5f);
        A1[co] = scale1 * inv1;  B1[co] = be1[co] - m1[co] * inv1;
        A2[co] = scale2 * inv2;  B2[co] = be2[co] - m2[co] * inv2;
        int pc1[9], pc2[9];
#pragma unroll
        for (int t = 0; t < 9; t++) {
            pc1[t] = spc1[0][t] + spc1[1][t] + spc1[2][t] + spc1[3][t];
            pc2[t] = spc2[0][t] + spc2[1][t] + spc2[2][t] + spc2[3][t];
        }
        int* c1 = C1s + co * 8;
        c1[0] = pc1[0] + pc1[1] + pc1[2];   // top row invalid
        c1[1] = pc1[6] + pc1[7] + pc1[8];   // bottom
        c1[2] = pc1[0] + pc1[3] + pc1[6];   // left col
        c1[3] = pc1[2] + pc1[5] + pc1[8];   // right col
        c1[4] = pc1[0]; c1[5] = pc1[2]; c1[6] = pc1[6]; c1[7] = pc1[8];
        int* c2 = C2s + co * 8;
        c2[0] = pc2[0] + pc2[1] + pc2[2];
        c2[1] = pc2[6] + pc2[7] + pc2[8];
        c2[2] = pc2[0] + pc2[3] + pc2[6];
        c2[3] = pc2[2] + pc2[5] + pc2[8];
        c2[4] = pc2[0]; c2[5] = pc2[2]; c2[6] = pc2[6]; c2[7] = pc2[8];
    }
}

// ---------------- zero the halo'd bit arrays ----------------
__global__ __launch_bounds__(256) void k_zero(ulonglong2* __restrict__ dst, int n)
{
    int i = blockIdx.x * 256 + threadIdx.x;
    if (i < n) { ulonglong2 z; z.x = 0; z.y = 0; dst[i] = z; }
}

// ---------------- activation packing into halo'd arrays ----------------
__global__ __launch_bounds__(256) void k_pack(
    const float* __restrict__ x, const float* __restrict__ mb,
    u64* __restrict__ bitsA, u64* __restrict__ bitsI)
{
    int tid = threadIdx.x;
    int p = blockIdx.x * 256 + tid;
    int q = blockIdx.y;
    int b = p / HWSZ, hw = p % HWSZ;
    int h = hw / WD, w = hw % WD;
    const float* xa = x + ((size_t)(b * 512 + q * 64)) * HWSZ + hw;
    const float* xi = x + ((size_t)(b * 512 + 256 + q * 64)) * HWSZ + hw;
    const float* mbq = mb + q * 64;
    u64 wa = 0, wi = 0;
#pragma unroll 8
    for (int j = 0; j < 64; j++) {
        float va = xa[(size_t)j * HWSZ];
        float vi = xi[(size_t)j * HWSZ] + mbq[j];
        wa |= (u64)(va >= 0.f) << j;
        wi |= (u64)(vi >= 0.f) << j;
    }
    size_t pos = ((size_t)b * IMG + (h + 1) * HS + (w + 1)) * 4 + q;
    bitsA[pos] = wa;
    bitsI[pos] = wi;
}

// ---------------- conv1: 256->256 binary conv + bn + residual + clip ----------------
// 4 waves: wave g owns co [q*64+g*16,+16); lane owns 2 adjacent px (w even)
__global__ __launch_bounds__(256, 4) void k_conv1(
    const float* __restrict__ x, const u64* __restrict__ bitsA,
    const u64* __restrict__ w1b, const float* __restrict__ A1,
    const float* __restrict__ B1, const int* __restrict__ C1s,
    u64* __restrict__ bitsC, u16* __restrict__ c1v)
{
    __shared__ __align__(16) u64 sw[2304];
    __shared__ float sA[64], sB[64];
    __shared__ int scr[512];
    __shared__ u16 spart[4][128];
    int tid = threadIdx.x, q = blockIdx.y, cobase = q * 64;
    {
        const u64* src = w1b + (size_t)cobase * 36;
#pragma unroll
        for (int i = 0; i < 9; i++) sw[tid + i * 256] = src[tid + i * 256];
        if (tid < 64) { sA[tid] = A1[cobase + tid]; sB[tid] = B1[cobase + tid]; }
        scr[tid] = C1s[cobase * 8 + tid];
        scr[tid + 256] = C1s[cobase * 8 + tid + 256];
    }
    __syncthreads();

    int wid = tid >> 6, lane = tid & 63;
    int gu = __builtin_amdgcn_readfirstlane(wid);
    int pix0 = blockIdx.x * 128 + lane * 2;
    int b = pix0 / HWSZ, hw = pix0 % HWSZ, h = hw / WD, w = hw % WD; // w even
    int base = b * IMG + (h + 1) * HS + w;

    int accA[8][2] = {}, accB[8][2] = {};
    conv_pass2(bitsA, sw, gu << 4, base, accA, accB);

    int mt = (h == 0), mbo = (h == WD - 1);
    int wl = (w == 0), wr = (w == 54);
    int nvr = 3 - mt - mbo;
    int nv0 = nvr * (3 - wl), nv1 = nvr * (3 - wr);

    unsigned sb0 = 0, sb1 = 0;
    bool wrv = (q < 2);
#pragma unroll
    for (int half = 0; half < 2; half++)
#pragma unroll
    for (int co = 0; co < 8; co++) {
        int col = (gu << 4) + half * 8 + co;
        int coG = cobase + col, bit = half * 8 + co;
        float A = sA[col], Bc = sB[col];
        const int* cs = &scr[col * 8];
        int a0 = half ? accB[co][0] : accA[co][0];
        int a1 = half ? accB[co][1] : accA[co][1];
        int ctb = (mt ? cs[0] : 0) + (mbo ? cs[1] : 0);
        int corr0 = ctb + (wl ? (cs[2] - (mt ? cs[4] : 0) - (mbo ? cs[6] : 0)) : 0);
        int corr1 = ctb + (wr ? (cs[3] - (mt ? cs[5] : 0) - (mbo ? cs[7] : 0)) : 0);
        float2 xr = *(const float2*)(x + ((size_t)(b * 512 + coG)) * HWSZ + hw);
        float v0 = (float)((nv0 << 8) + 2 * (corr0 - a0)) * A + Bc + xr.x;
        float v1 = (float)((nv1 << 8) + 2 * (corr1 - a1)) * A + Bc + xr.y;
        sb0 |= (unsigned)(v0 >= 0.f) << bit;
        sb1 |= (unsigned)(v1 >= 0.f) << bit;
        if (wrv) {
            ushort2 st; st.x = f2bf(clampf(v0)); st.y = f2bf(clampf(v1));
            *(ushort2*)(c1v + (size_t)coG * NPIX + pix0) = st;
        }
    }
    spart[wid][lane * 2]     = (u16)sb0;
    spart[wid][lane * 2 + 1] = (u16)sb1;
    __syncthreads();
    if (wid == 0) {
#pragma unroll
        for (int p = 0; p < 2; p++) {
            int pi = lane * 2 + p;
            u64 word = (u64)spart[0][pi] | ((u64)spart[1][pi] << 16)
                     | ((u64)spart[2][pi] << 32) | ((u64)spart[3][pi] << 48);
            bitsC[(size_t)(base + 1 + p) * 4 + q] = word;
        }
    }
}

// ---------------- conv2: 512->256 binary conv + bn + shuffled residual + clip ----------------
__global__ __launch_bounds__(256, 4) void k_conv2(
    const float* __restrict__ x, const float* __restrict__ mb,
    const u64* __restrict__ bitsC, const u64* __restrict__ bitsI,
    const u64* __restrict__ w2e, const u64* __restrict__ w2o,
    const float* __restrict__ A2, const float* __restrict__ B2,
    const int* __restrict__ C2s,
    const u16* __restrict__ c1v, float* __restrict__ out)
{
    __shared__ __align__(16) u64 se[2304], so[2304];
    __shared__ float sA[64], sB[64], sM[32];
    __shared__ int scr[512];
    int tid = threadIdx.x, q = blockIdx.y, cobase = q * 64;
    {
        const u64* srcE = w2e + (size_t)cobase * 36;
        const u64* srcO = w2o + (size_t)cobase * 36;
#pragma unroll
        for (int i = 0; i < 9; i++) { se[tid + i * 256] = srcE[tid + i * 256]; so[tid + i * 256] = srcO[tid + i * 256]; }
        if (tid < 64) { sA[tid] = A2[cobase + tid]; sB[tid] = B2[cobase + tid]; }
        if (tid >= 64 && tid < 96) sM[tid - 64] = mb[q * 32 + tid - 64];
        scr[tid] = C2s[cobase * 8 + tid];
        scr[tid + 256] = C2s[cobase * 8 + tid + 256];
    }
    __syncthreads();

    int wid = tid >> 6, lane = tid & 63;
    int gu = __builtin_amdgcn_readfirstlane(wid);
    int pix0 = blockIdx.x * 128 + lane * 2;
    int b = pix0 / HWSZ, hw = pix0 % HWSZ, h = hw / WD, w = hw % WD;
    int base = b * IMG + (h + 1) * HS + w;

    int accA[8][2] = {}, accB[8][2] = {};
    conv_pass2(bitsC, se, gu << 4, base, accA, accB);
    conv_pass2(bitsI, so, gu << 4, base, accA, accB);

    int mt = (h == 0), mbo = (h == WD - 1);
    int wl = (w == 0), wr = (w == 54);
    int nvr = 3 - mt - mbo;
    int nv0 = nvr * (3 - wl), nv1 = nvr * (3 - wr);

#pragma unroll
    for (int half = 0; half < 2; half++)
#pragma unroll
    for (int co = 0; co < 8; co++) {
        int col = (gu << 4) + half * 8 + co;
        int coG = cobase + col, cg2 = coG >> 1;
        float A = sA[col], Bc = sB[col];
        const int* cs = &scr[col * 8];
        int a0 = half ? accB[co][0] : accA[co][0];
        int a1 = half ? accB[co][1] : accA[co][1];
        int ctb = (mt ? cs[0] : 0) + (mbo ? cs[1] : 0);
        int corr0 = ctb + (wl ? (cs[2] - (mt ? cs[4] : 0) - (mbo ? cs[6] : 0)) : 0);
        int corr1 = ctb + (wr ? (cs[3] - (mt ? cs[5] : 0) - (mbo ? cs[7] : 0)) : 0);
        float r0, r1;
        if ((co & 1) == 0) {   // coG even -> conv1 output residual
            ushort2 cv = *(const ushort2*)(c1v + (size_t)cg2 * NPIX + pix0);
            r0 = bf2f(cv.x); r1 = bf2f(cv.y);
        } else {               // coG odd -> idle branch residual
            float2 xi = *(const float2*)(x + ((size_t)(b * 512 + 256 + cg2)) * HWSZ + hw);
            float mv = sM[col >> 1];
            r0 = xi.x + mv; r1 = xi.y + mv;
        }
        float2 ov;
        ov.x = clampf((float)((nv0 << 9) + 2 * (corr0 - a0)) * A + Bc + r0);
        ov.y = clampf((float)((nv1 << 9) + 2 * (corr1 - a1)) * A + Bc + r1);
        *(float2*)(out + ((size_t)(b * 256 + coG)) * HWSZ + hw) = ov;
    }
}

extern "C" void kernel_launch(void* const* d_in, const int* in_sizes, int n_in,
                              void* d_out, int out_size, void* d_ws, size_t ws_size,
                              hipStream_t stream)
{
    const float* x   = (const float*)d_in[0];
    const float* w1  = (const float*)d_in[1];
    const float* w2  = (const float*)d_in[2];
    const float* g1  = (const float*)d_in[3];
    const float* be1 = (const float*)d_in[4];
    const float* m1  = (const float*)d_in[5];
    const float* v1  = (const float*)d_in[6];
    const float* g2  = (const float*)d_in[7];
    const float* be2 = (const float*)d_in[8];
    const float* m2  = (const float*)d_in[9];
    const float* v2  = (const float*)d_in[10];
    const float* mb  = (const float*)d_in[11];

    char* ws = (char*)d_ws;
    u64* w1b = (u64*)ws; ws += 73728;
    u64* w2e = (u64*)ws; ws += 73728;
    u64* w2o = (u64*)ws; ws += 73728;
    float* A1 = (float*)ws; ws += 1024;
    float* B1 = (float*)ws; ws += 1024;
    float* A2 = (float*)ws; ws += 1024;
    float* B2 = (float*)ws; ws += 1024;
    int* C1s = (int*)ws; ws += 8192;
    int* C2s = (int*)ws; ws += 8192;
    u64* bitsA = (u64*)ws; ws += (size_t)16 * IMG * 4 * 8;   // 1,722,368 B
    u64* bitsI = (u64*)ws; ws += (size_t)16 * IMG * 4 * 8;
    u64* bitsC = (u64*)ws; ws += (size_t)16 * IMG * 4 * 8;
    u16* c1v = (u16*)ws; ws += (size_t)128 * NPIX * 2;

    int nzero2 = (int)(3 * (size_t)16 * IMG * 4 * 8 / 16);   // 322,944 ulonglong2

    hipLaunchKernelGGL(k_wprep, dim3(256), dim3(256), 0, stream,
                       w1, w2, g1, be1, m1, v1, g2, be2, m2, v2,
                       w1b, w2e, w2o, A1, B1, A2, B2, C1s, C2s);
    hipLaunchKernelGGL(k_zero, dim3((nzero2 + 255) / 256), dim3(256), 0, stream,
                       (ulonglong2*)bitsA, nzero2);
    hipLaunchKernelGGL(k_pack, dim3(196, 4), dim3(256), 0, stream, x, mb, bitsA, bitsI);
    hipLaunchKernelGGL(k_conv1, dim3(392, 4), dim3(256), 0, stream,
                       x, bitsA, w1b, A1, B1, C1s, bitsC, c1v);
    hipLaunchKernelGGL(k_conv2, dim3(392, 4), dim3(256), 0, stream,
                       x, mb, bitsC, bitsI, w2e, w2o, A2, B2, C2s, c1v, (float*)d_out);
}

// Round 11
// 436.529 us; speedup vs baseline: 1.1090x; 1.0046x over previous
//
#include <hip/hip_runtime.h>
#include <cstdint>

typedef unsigned long long u64;
typedef unsigned int u32;
typedef unsigned short u16;
typedef unsigned char u8;

#define HWSZ 3136      // 56*56
#define WD 56
#define NPIX 50176     // 16*3136
#define HS 58          // halo row stride
#define IMG 3364       // 58*58 positions per image

__device__ __forceinline__ float clampf(float v){ return fminf(1.0f, fmaxf(-1.0f, v)); }
__device__ __forceinline__ u16 f2bf(float f){
    unsigned u = __float_as_uint(f);
    return (u16)((u + 0x7fffu + ((u >> 16) & 1u)) >> 16);
}
__device__ __forceinline__ float bf2f(u16 h){ return __uint_as_float(((unsigned)h) << 16); }
// xor + chained popcount: 2 v_xor + 2 v_bcnt (accumulate folds into bcnt src1)
__device__ __forceinline__ int xp(u64 a, u64 b, int s){
    u64 x = a ^ b;
    s += __popc((unsigned)x);
    s += __popc((unsigned)(x >> 32));
    return s;
}

// 3x3 binary conv, 8 out-channels x 4 adjacent pixels per lane, halo'd bits.
__device__ __forceinline__ void conv_pass84(
    const u64* __restrict__ bits, const u64* wlds, int colbase,
    int base, int (&acc)[8][4])
{
#pragma unroll 1
    for (int dy = -1; dy <= 1; dy++) {
        const ulonglong2* rp = (const ulonglong2*)(bits + (size_t)(base + dy * HS) * 4);
        ulonglong2 plo[6], phi[6];
#pragma unroll
        for (int k = 0; k < 6; k++) { plo[k] = rp[2 * k]; phi[k] = rp[2 * k + 1]; }
#pragma unroll
        for (int dx = 0; dx < 3; dx++) {
            int t = (dy + 1) * 3 + dx;
#pragma unroll
            for (int co = 0; co < 8; co++) {
                const ulonglong2* wp = (const ulonglong2*)&wlds[((colbase + co) * 9 + t) * 4];
                ulonglong2 wA = wp[0], wB = wp[1];
#pragma unroll
                for (int p = 0; p < 4; p++) {
                    int k = dx + p; int s = acc[co][p];
                    s = xp(plo[k].x, wA.x, s); s = xp(plo[k].y, wA.y, s);
                    s = xp(phi[k].x, wB.x, s); s = xp(phi[k].y, wB.y, s);
                    acc[co][p] = s;
                }
            }
        }
    }
}

// ---------------- weight prep: pack sign bits, fold bn, border-correction sums ----
__global__ __launch_bounds__(256) void k_wprep(
    const float* __restrict__ w1, const float* __restrict__ w2,
    const float* __restrict__ g1, const float* __restrict__ be1,
    const float* __restrict__ m1, const float* __restrict__ v1,
    const float* __restrict__ g2, const float* __restrict__ be2,
    const float* __restrict__ m2, const float* __restrict__ v2,
    u64* __restrict__ w1b, u64* __restrict__ w2e, u64* __restrict__ w2o,
    float* __restrict__ A1, float* __restrict__ B1,
    float* __restrict__ A2, float* __restrict__ B2,
    int* __restrict__ C1s, int* __restrict__ C2s)
{
    int co  = blockIdx.x;
    int tid = threadIdx.x;
    int wv = tid >> 6, lane = tid & 63;
    int ci = (wv << 6) + lane;

    __shared__ int spc1[4][9], spc2[4][9];

    float s1 = 0.f, s2 = 0.f;
    const float* w1p = w1 + ((size_t)co * 256 + ci) * 9;
#pragma unroll
    for (int t = 0; t < 9; t++) {
        float v = w1p[t];
        s1 += fabsf(v);
        u64 bal = __ballot(v >= 0.f);
        if (lane == 0) { w1b[(co * 9 + t) * 4 + wv] = bal; spc1[wv][t] = __popcll(bal); }
    }
    const float* wep = w2 + ((size_t)co * 512 + 2 * ci) * 9;
    const float* wop = wep + 9;
#pragma unroll
    for (int t = 0; t < 9; t++) {
        float ve = wep[t], vo = wop[t];
        s2 += fabsf(ve) + fabsf(vo);
        u64 bale = __ballot(ve >= 0.f);
        u64 balo = __ballot(vo >= 0.f);
        if (lane == 0) {
            w2e[(co * 9 + t) * 4 + wv] = bale; w2o[(co * 9 + t) * 4 + wv] = balo;
            spc2[wv][t] = __popcll(bale) + __popcll(balo);
        }
    }
    __shared__ float red1[256], red2[256];
    red1[tid] = s1; red2[tid] = s2;
    __syncthreads();
    for (int off = 128; off > 0; off >>= 1) {
        if (tid < off) { red1[tid] += red1[tid + off]; red2[tid] += red2[tid + off]; }
        __syncthreads();
    }
    if (tid == 0) {
        float scale1 = red1[0] / 2304.f;
        float scale2 = red2[0] / 4608.f;
        float inv1 = g1[co] / sqrtf(v1[co] + 1e-5f);
        float inv2 = g2[co] / sqrtf(v2[co] + 1e-5f);
        A1[co] = scale1 * inv1;  B1[co] = be1[co] - m1[co] * inv1;
        A2[co] = scale2 * inv2;  B2[co] = be2[co] - m2[co] * inv2;
        int pc1[9], pc2[9];
#pragma unroll
        for (int t = 0; t < 9; t++) {
            pc1[t] = spc1[0][t] + spc1[1][t] + spc1[2][t] + spc1[3][t];
            pc2[t] = spc2[0][t] + spc2[1][t] + spc2[2][t] + spc2[3][t];
        }
        int* c1 = C1s + co * 8;
        c1[0] = pc1[0] + pc1[1] + pc1[2];   // top row invalid
        c1[1] = pc1[6] + pc1[7] + pc1[8];   // bottom
        c1[2] = pc1[0] + pc1[3] + pc1[6];   // left col
        c1[3] = pc1[2] + pc1[5] + pc1[8];   // right col
        c1[4] = pc1[0]; c1[5] = pc1[2]; c1[6] = pc1[6]; c1[7] = pc1[8];
        int* c2 = C2s + co * 8;
        c2[0] = pc2[0] + pc2[1] + pc2[2];
        c2[1] = pc2[6] + pc2[7] + pc2[8];
        c2[2] = pc2[0] + pc2[3] + pc2[6];
        c2[3] = pc2[2] + pc2[5] + pc2[8];
        c2[4] = pc2[0]; c2[5] = pc2[2]; c2[6] = pc2[6]; c2[7] = pc2[8];
    }
}

// ---------------- zero the halo'd bit arrays ----------------
__global__ __launch_bounds__(256) void k_zero(ulonglong2* __restrict__ dst, int n)
{
    int i = blockIdx.x * 256 + threadIdx.x;
    if (i < n) { ulonglong2 z; z.x = 0; z.y = 0; dst[i] = z; }
}

// ---------------- activation packing into halo'd arrays ----------------
__global__ __launch_bounds__(256) void k_pack(
    const float* __restrict__ x, const float* __restrict__ mb,
    u64* __restrict__ bitsA, u64* __restrict__ bitsI)
{
    int tid = threadIdx.x;
    int p = blockIdx.x * 256 + tid;
    int q = blockIdx.y;
    int b = p / HWSZ, hw = p % HWSZ;
    int h = hw / WD, w = hw % WD;
    const float* xa = x + ((size_t)(b * 512 + q * 64)) * HWSZ + hw;
    const float* xi = x + ((size_t)(b * 512 + 256 + q * 64)) * HWSZ + hw;
    const float* mbq = mb + q * 64;
    u64 wa = 0, wi = 0;
#pragma unroll 8
    for (int j = 0; j < 64; j++) {
        float va = xa[(size_t)j * HWSZ];
        float vi = xi[(size_t)j * HWSZ] + mbq[j];
        wa |= (u64)(va >= 0.f) << j;
        wi |= (u64)(vi >= 0.f) << j;
    }
    size_t pos = ((size_t)b * IMG + (h + 1) * HS + (w + 1)) * 4 + q;
    bitsA[pos] = wa;
    bitsI[pos] = wi;
}

// ---------------- conv1: 256->256 binary conv + bn + residual + clip ----------------
// blockIdx.y owns 32 co; 4 waves x 8 co; lane owns 4 adjacent px (w%4==0)
__global__ __launch_bounds__(256, 4) void k_conv1(
    const float* __restrict__ x, const u64* __restrict__ bitsA,
    const u64* __restrict__ w1b, const float* __restrict__ A1,
    const float* __restrict__ B1, const int* __restrict__ C1s,
    u32* __restrict__ bitsC32, u16* __restrict__ c1v)
{
    __shared__ __align__(16) u64 sw[1152];   // 32 co * 9 taps * 4 words
    __shared__ float sA[32], sB[32];
    __shared__ int scr[256];
    __shared__ u8 spart[4][256];
    int tid = threadIdx.x, y = blockIdx.y, cog = y * 32;
    {
        const u64* src = w1b + (size_t)cog * 36;
        for (int i = tid; i < 1152; i += 256) sw[i] = src[i];
        if (tid < 32) { sA[tid] = A1[cog + tid]; sB[tid] = B1[cog + tid]; }
        scr[tid] = C1s[cog * 8 + tid];
    }
    __syncthreads();

    int wid = tid >> 6, lane = tid & 63;
    int gu = __builtin_amdgcn_readfirstlane(wid);
    int pix0 = blockIdx.x * 256 + lane * 4;
    int b = pix0 / HWSZ, hw = pix0 % HWSZ, h = hw / WD, w = hw % WD; // w%4==0
    int base = b * IMG + (h + 1) * HS + w;

    int acc[8][4] = {};
    conv_pass84(bitsA, sw, gu << 3, base, acc);

    int mt = (h == 0), mbo = (h == WD - 1);
    int wl = (w == 0), wrr = (w == 52);      // right edge hits p==3
    int nvr = 3 - mt - mbo;
    int nv[4];
#pragma unroll
    for (int p = 0; p < 4; p++) {
        int wp_ = w + p;
        nv[p] = nvr * (3 - (wp_ == 0) - (wp_ == WD - 1));
    }

    u32 sb[4] = {0, 0, 0, 0};
    bool wrv = (y < 4);
#pragma unroll
    for (int co = 0; co < 8; co++) {
        int col = (gu << 3) + co;
        int coG = cog + col;
        float A = sA[col], Bc = sB[col];
        const int* cs = &scr[col * 8];
        int ctb = (mt ? cs[0] : 0) + (mbo ? cs[1] : 0);
        int L = wl  ? (cs[2] - (mt ? cs[4] : 0) - (mbo ? cs[6] : 0)) : 0;
        int R = wrr ? (cs[3] - (mt ? cs[5] : 0) - (mbo ? cs[7] : 0)) : 0;
        float4 xr = *(const float4*)(x + ((size_t)(b * 512 + coG)) * HWSZ + hw);
        float v0 = (float)((nv[0] << 8) + 2 * (ctb + L - acc[co][0])) * A + Bc + xr.x;
        float v1 = (float)((nv[1] << 8) + 2 * (ctb     - acc[co][1])) * A + Bc + xr.y;
        float v2 = (float)((nv[2] << 8) + 2 * (ctb     - acc[co][2])) * A + Bc + xr.z;
        float v3 = (float)((nv[3] << 8) + 2 * (ctb + R - acc[co][3])) * A + Bc + xr.w;
        sb[0] |= (u32)(v0 >= 0.f) << co;
        sb[1] |= (u32)(v1 >= 0.f) << co;
        sb[2] |= (u32)(v2 >= 0.f) << co;
        sb[3] |= (u32)(v3 >= 0.f) << co;
        if (wrv) {
            ushort4 st;
            st.x = f2bf(clampf(v0)); st.y = f2bf(clampf(v1));
            st.z = f2bf(clampf(v2)); st.w = f2bf(clampf(v3));
            *(ushort4*)(c1v + (size_t)coG * NPIX + pix0) = st;
        }
    }
#pragma unroll
    for (int p = 0; p < 4; p++) spart[wid][lane * 4 + p] = (u8)sb[p];
    __syncthreads();
    if (wid == 0) {
#pragma unroll
        for (int p = 0; p < 4; p++) {
            int pi = lane * 4 + p;
            u32 word = (u32)spart[0][pi] | ((u32)spart[1][pi] << 8)
                     | ((u32)spart[2][pi] << 16) | ((u32)spart[3][pi] << 24);
            bitsC32[(size_t)(base + 1 + p) * 8 + y] = word;
        }
    }
}

// ---------------- conv2: 512->256 binary conv + bn + shuffled residual + clip ----------------
__global__ __launch_bounds__(256, 4) void k_conv2(
    const float* __restrict__ x, const float* __restrict__ mb,
    const u64* __restrict__ bitsC, const u64* __restrict__ bitsI,
    const u64* __restrict__ w2e, const u64* __restrict__ w2o,
    const float* __restrict__ A2, const float* __restrict__ B2,
    const int* __restrict__ C2s,
    const u16* __restrict__ c1v, float* __restrict__ out)
{
    __shared__ __align__(16) u64 se[1152], so[1152];
    __shared__ float sA[32], sB[32], sM[16];
    __shared__ int scr[256];
    int tid = threadIdx.x, y = blockIdx.y, cog = y * 32;
    {
        const u64* srcE = w2e + (size_t)cog * 36;
        const u64* srcO = w2o + (size_t)cog * 36;
        for (int i = tid; i < 1152; i += 256) { se[i] = srcE[i]; so[i] = srcO[i]; }
        if (tid < 32) { sA[tid] = A2[cog + tid]; sB[tid] = B2[cog + tid]; }
        if (tid >= 32 && tid < 48) sM[tid - 32] = mb[cog / 2 + tid - 32];
        scr[tid] = C2s[cog * 8 + tid];
    }
    __syncthreads();

    int wid = tid >> 6, lane = tid & 63;
    int gu = __builtin_amdgcn_readfirstlane(wid);
    int pix0 = blockIdx.x * 256 + lane * 4;
    int b = pix0 / HWSZ, hw = pix0 % HWSZ, h = hw / WD, w = hw % WD;
    int base = b * IMG + (h + 1) * HS + w;

    int acc[8][4] = {};
    conv_pass84(bitsC, se, gu << 3, base, acc);
    conv_pass84(bitsI, so, gu << 3, base, acc);

    int mt = (h == 0), mbo = (h == WD - 1);
    int wl = (w == 0), wrr = (w == 52);
    int nvr = 3 - mt - mbo;
    int nv[4];
#pragma unroll
    for (int p = 0; p < 4; p++) {
        int wp_ = w + p;
        nv[p] = nvr * (3 - (wp_ == 0) - (wp_ == WD - 1));
    }

#pragma unroll
    for (int co = 0; co < 8; co++) {
        int col = (gu << 3) + co;
        int coG = cog + col, cg2 = coG >> 1;
        float A = sA[col], Bc = sB[col];
        const int* cs = &scr[col * 8];
        int ctb = (mt ? cs[0] : 0) + (mbo ? cs[1] : 0);
        int L = wl  ? (cs[2] - (mt ? cs[4] : 0) - (mbo ? cs[6] : 0)) : 0;
        int R = wrr ? (cs[3] - (mt ? cs[5] : 0) - (mbo ? cs[7] : 0)) : 0;
        float r0, r1, r2, r3;
        if ((col & 1) == 0) {   // coG even -> conv1 output residual
            ushort4 cv = *(const ushort4*)(c1v + (size_t)cg2 * NPIX + pix0);
            r0 = bf2f(cv.x); r1 = bf2f(cv.y); r2 = bf2f(cv.z); r3 = bf2f(cv.w);
        } else {                // coG odd -> idle branch residual
            float4 xi = *(const float4*)(x + ((size_t)(b * 512 + 256 + cg2)) * HWSZ + hw);
            float mv = sM[col >> 1];
            r0 = xi.x + mv; r1 = xi.y + mv; r2 = xi.z + mv; r3 = xi.w + mv;
        }
        float4 ov;
        ov.x = clampf((float)((nv[0] << 9) + 2 * (ctb + L - acc[co][0])) * A + Bc + r0);
        ov.y = clampf((float)((nv[1] << 9) + 2 * (ctb     - acc[co][1])) * A + Bc + r1);
        ov.z = clampf((float)((nv[2] << 9) + 2 * (ctb     - acc[co][2])) * A + Bc + r2);
        ov.w = clampf((float)((nv[3] << 9) + 2 * (ctb + R - acc[co][3])) * A + Bc + r3);
        *(float4*)(out + ((size_t)(b * 256 + coG)) * HWSZ + hw) = ov;
    }
}

extern "C" void kernel_launch(void* const* d_in, const int* in_sizes, int n_in,
                              void* d_out, int out_size, void* d_ws, size_t ws_size,
                              hipStream_t stream)
{
    const float* x   = (const float*)d_in[0];
    const float* w1  = (const float*)d_in[1];
    const float* w2  = (const float*)d_in[2];
    const float* g1  = (const float*)d_in[3];
    const float* be1 = (const float*)d_in[4];
    const float* m1  = (const float*)d_in[5];
    const float* v1  = (const float*)d_in[6];
    const float* g2  = (const float*)d_in[7];
    const float* be2 = (const float*)d_in[8];
    const float* m2  = (const float*)d_in[9];
    const float* v2  = (const float*)d_in[10];
    const float* mb  = (const float*)d_in[11];

    char* ws = (char*)d_ws;
    u64* w1b = (u64*)ws; ws += 73728;
    u64* w2e = (u64*)ws; ws += 73728;
    u64* w2o = (u64*)ws; ws += 73728;
    float* A1 = (float*)ws; ws += 1024;
    float* B1 = (float*)ws; ws += 1024;
    float* A2 = (float*)ws; ws += 1024;
    float* B2 = (float*)ws; ws += 1024;
    int* C1s = (int*)ws; ws += 8192;
    int* C2s = (int*)ws; ws += 8192;
    u64* bitsA = (u64*)ws; ws += (size_t)16 * IMG * 4 * 8;   // 1,722,368 B
    u64* bitsI = (u64*)ws; ws += (size_t)16 * IMG * 4 * 8;
    u64* bitsC = (u64*)ws; ws += (size_t)16 * IMG * 4 * 8;
    u16* c1v = (u16*)ws; ws += (size_t)128 * NPIX * 2;

    int nzero2 = (int)(3 * (size_t)16 * IMG * 4 * 8 / 16);   // 322,944 ulonglong2

    hipLaunchKernelGGL(k_wprep, dim3(256), dim3(256), 0, stream,
                       w1, w2, g1, be1, m1, v1, g2, be2, m2, v2,
                       w1b, w2e, w2o, A1, B1, A2, B2, C1s, C2s);
    hipLaunchKernelGGL(k_zero, dim3((nzero2 + 255) / 256), dim3(256), 0, stream,
                       (ulonglong2*)bitsA, nzero2);
    hipLaunchKernelGGL(k_pack, dim3(196, 4), dim3(256), 0, stream, x, mb, bitsA, bitsI);
    hipLaunchKernelGGL(k_conv1, dim3(196, 8), dim3(256), 0, stream,
                       x, bitsA, w1b, A1, B1, C1s, (u32*)bitsC, c1v);
    hipLaunchKernelGGL(k_conv2, dim3(196, 8), dim3(256), 0, stream,
                       x, mb, bitsC, bitsI, w2e, w2o, A2, B2, C2s, c1v, (float*)d_out);
}